// Round 9
// baseline (129.471 us; speedup 1.0000x reference)
//
#include <hip/hip_runtime.h>

using half8 = __attribute__((ext_vector_type(8))) _Float16;
using f32x4 = __attribute__((ext_vector_type(4))) float;

#define Lc 4096
#define Ec 64
#define Mc 64
#define BHc 128

// 2*pi/4096
#define TWO_PI_OVER_L 1.5339807878856412e-3f

// ---------------------------------------------------------------------------
// Twiddle tables:
//   Tt  tile-major: Tt2[lb][m2][l6], lb=l/64, l6=l%64, m2 in [0,128):
//       rows 0..63 = cos(th), 64..127 = -sin(th).  (A-panel pre-pack: a wave's
//       A-fragment load is 16 rows x 128B = contiguous 2KB -> all channels.)
//   UL[l][m2] f16: cols 0..63 = cos(th), cols 64..127 = +sin(th)
// th = 2*pi*k_m*l/L
// ---------------------------------------------------------------------------
__global__ __launch_bounds__(256) void twid_k(const int* __restrict__ idx,
                                              _Float16* __restrict__ Tt,
                                              _Float16* __restrict__ UL) {
    int id = blockIdx.x * 256 + threadIdx.x;   // 0 .. 524287
    {   // UL pass: l = id>>7, m2 = id&127  (coalesced in m2)
        int l = id >> 7, m2 = id & 127, m = m2 & 63;
        int k = idx[m];
        int ph = (k * l) & (Lc - 1);
        float s, c;
        sincosf((float)ph * TWO_PI_OVER_L, &s, &c);
        UL[id] = (_Float16)((m2 >= 64) ? s : c);
    }
    {   // Tt2 pass: lb = id>>13, m2 = (id>>6)&127, l6 = id&63 (write coalesced)
        int lb = id >> 13, m2 = (id >> 6) & 127, l6 = id & 63;
        int l = lb * 64 + l6, m = m2 & 63;
        int k = idx[m];
        int ph = (k * l) & (Lc - 1);
        float s, c;
        sincosf((float)ph * TWO_PI_OVER_L, &s, &c);
        Tt[id] = (_Float16)((m2 >= 64) ? -s : c);
    }
}

// ---------------------------------------------------------------------------
// Forward: selP[ch][bh][m2=128][e=64] = sum_{l in chunk} T[m2][l] * x[bh][l][e]
// grid (BHc, NCH), 256 thr (4 waves). Wave w owns m2 rows [32w, 32w+32).
// r8 pipeline (dbuf LDS, 1 barrier/tile, 2-tile-ahead register prefetch) +
// r9 change: A-panel from tile-major Tt2 -> contiguous 2KB per wave A-load.
// xs layout: [e][l] f16, row = 128B, byte ^= ((e&7)<<4).
// ---------------------------------------------------------------------------
#define LOADT(SET, S) do{                                                     \
    const float* g0_ = xp + (size_t)((S) * 64 + 2 * lp) * Ec;                 \
    const float* g1_ = xp + (size_t)((S) * 64 + 2 * lp + 32) * Ec;            \
    ra[SET][0] = *(const float4*)g0_;  rb[SET][0] = *(const float4*)(g0_ + Ec);\
    ra[SET][1] = *(const float4*)g1_;  rb[SET][1] = *(const float4*)(g1_ + Ec);\
}while(0)

#define PACKT(SET, BUF) do{                                                   \
    _Pragma("unroll")                                                         \
    for (int i_ = 0; i_ < 2; ++i_) {                                          \
        const float* pa_ = (const float*)&ra[SET][i_];                        \
        const float* pb_ = (const float*)&rb[SET][i_];                        \
        unsigned int pk_[4];                                                  \
        _Pragma("unroll")                                                     \
        for (int j_ = 0; j_ < 4; ++j_) {                                      \
            unsigned short ua_ = __builtin_bit_cast(unsigned short, (_Float16)pa_[j_]); \
            unsigned short ub_ = __builtin_bit_cast(unsigned short, (_Float16)pb_[j_]); \
            pk_[j_] = ua_ | ((unsigned int)ub_ << 16);                        \
        }                                                                     \
        _Pragma("unroll")                                                     \
        for (int j_ = 0; j_ < 4; ++j_) {                                      \
            int jr_ = (j_ + col4) & 3;                                        \
            int e_  = col4 * 4 + jr_;                                         \
            int byt_ = (e_ * 128 + lp * 4 + i_ * 64) ^ ((e_ & 7) << 4);       \
            *(unsigned int*)((char*)xs[BUF] + byt_) = pk_[jr_];               \
        }                                                                     \
    }                                                                         \
}while(0)

#define MFMA_STEP(S, BUF) do{                                                 \
    _Pragma("unroll")                                                         \
    for (int ks_ = 0; ks_ < 2; ++ks_) {                                       \
        half8 A0_ = *(const half8*)(tp + (size_t)(S) * 8192 + ks_ * 32);      \
        half8 A1_ = *(const half8*)(tp + (size_t)(S) * 8192 + 1024 + ks_ * 32); \
        _Pragma("unroll")                                                     \
        for (int j_ = 0; j_ < 4; ++j_) {                                      \
            int rbyt_ = ((16 * j_ + lo16) * 128 + ks_ * 64 + kg * 16) ^ ((lo16 & 7) << 4); \
            half8 Bv_ = *(const half8*)((const char*)xs[BUF] + rbyt_);        \
            acc[0][j_] = __builtin_amdgcn_mfma_f32_16x16x32_f16(A0_, Bv_, acc[0][j_], 0, 0, 0); \
            acc[1][j_] = __builtin_amdgcn_mfma_f32_16x16x32_f16(A1_, Bv_, acc[1][j_], 0, 0, 0); \
        }                                                                     \
    }                                                                         \
}while(0)

template<int NCH>
__global__ __launch_bounds__(256) void fwd_k(const float* __restrict__ x,
                                             const _Float16* __restrict__ Tt,
                                             float* __restrict__ selP) {
    constexpr int CH = Lc / NCH;
    constexpr int NT = CH / 64;                // 8 at NCH=8 (even)
    __shared__ _Float16 xs[2][64 * 64];        // 2 x 8KB
    int bh = blockIdx.x, ch = blockIdx.y;
    int tid = threadIdx.x;
    int lane = tid & 63, w = tid >> 6;
    int lo16 = lane & 15, kg = lane >> 4;
    int col4 = tid & 15, lp = tid >> 4;        // staging: e4=col4*4, row-pair lp

    const float* xp = x + ((size_t)bh * Lc + (size_t)ch * CH) * Ec + col4 * 4;
    // Tt2[lb][m2][l6]: block's first tile is lb0 = ch*CH/64; wave w rows 32w..
    const _Float16* tp = Tt + (size_t)(ch * (CH / 64)) * 8192
                            + (size_t)(w * 32 + lo16) * 64 + kg * 8;

    float4 ra[2][2], rb[2][2];                 // [regset][i]
    LOADT(0, 0);                               // tile 0 -> set0
    LOADT(1, 1);                               // tile 1 -> set1
    PACKT(0, 0);                               // tile 0 -> buf0
    __syncthreads();

    f32x4 acc[2][4] = {};
    for (int t = 0; t < NT / 2; ++t) {
        int s0 = 2 * t, s1 = 2 * t + 1;
        // ---- even tile: compute buf0 (tile s0), fill buf1 (tile s0+1) ----
        if (s0 + 2 < NT) LOADT(0, s0 + 2);     // tile s0+2 -> set0 (free)
        PACKT(1, 1);                           // tile s0+1 (set1) -> buf1
        MFMA_STEP(s0, 0);
        __syncthreads();
        // ---- odd tile: compute buf1 (tile s1), fill buf0 (tile s1+1) ----
        if (s1 + 2 < NT) LOADT(1, s1 + 2);     // tile s1+2 -> set1 (free)
        if (s1 + 1 < NT) PACKT(0, 0);          // tile s1+1 (set0) -> buf0
        MFMA_STEP(s1, 1);
        __syncthreads();
    }

    float* op = selP + (size_t)(ch * BHc + bh) * (128 * Ec);
    #pragma unroll
    for (int a = 0; a < 2; ++a)
        #pragma unroll
        for (int j = 0; j < 4; ++j)
            #pragma unroll
            for (int r = 0; r < 4; ++r) {
                int m2 = w * 32 + a * 16 + kg * 4 + r;
                int e  = 16 * j + lo16;
                op[m2 * Ec + e] = acc[a][j][r];
            }
}

// ---------------------------------------------------------------------------
// Mix: reduce K-partials, apply complex weight einsum, fold irfft scale.
// Vt[bh][o=64][m2=128] f16: cols 0..63 = s*Re(out_sel), 64..127 = -s*Im(out_sel)
// grid (BHc, 2) o-halves, 256 thr. Thread owns 4 o x 2 m.
// ---------------------------------------------------------------------------
__global__ __launch_bounds__(256) void mix_k(const float* __restrict__ selP,
                                             const float* __restrict__ wgt,
                                             const int* __restrict__ idx,
                                             _Float16* __restrict__ Vt, int nch) {
    __shared__ float sel_s[128 * 65];          // [m2][65] padded, 33.3KB
    int bh = blockIdx.x, oh = blockIdx.y;
    int tid = threadIdx.x;
    #pragma unroll
    for (int i = 0; i < 8; ++i) {
        int f4 = i * 256 + tid;                // 2048 float4 = 8192 floats
        float4 a = make_float4(0.f, 0.f, 0.f, 0.f);
        for (int chn = 0; chn < nch; ++chn) {
            float4 v = *((const float4*)(selP + (size_t)(chn * BHc + bh) * 8192) + f4);
            a.x += v.x; a.y += v.y; a.z += v.z; a.w += v.w;
        }
        int m2 = f4 >> 4, e4 = (f4 & 15) * 4;
        float* dst = &sel_s[m2 * 65 + e4];
        dst[0] = a.x; dst[1] = a.y; dst[2] = a.z; dst[3] = a.w;
    }
    __syncthreads();
    int og = tid & 7, mg = tid >> 3;
    int o0 = oh * 32 + og * 4;
    int m0 = mg * 2;
    float rR[4][2] = {{0}}, rI[4][2] = {{0}};
    for (int e = 0; e < Ec; ++e) {
        float sr0 = sel_s[m0 * 65 + e];
        float sr1 = sel_s[(m0 + 1) * 65 + e];
        float si0 = sel_s[(64 + m0) * 65 + e];
        float si1 = sel_s[(64 + m0 + 1) * 65 + e];
        #pragma unroll
        for (int i = 0; i < 4; ++i) {
            const float4* wp = (const float4*)&wgt[(((size_t)e * Ec + (o0 + i)) * Mc + m0) * 2];
            float4 wv = *wp;   // wR[m0], wI[m0], wR[m0+1], wI[m0+1]
            rR[i][0] += sr0 * wv.x - si0 * wv.y;
            rI[i][0] += sr0 * wv.y + si0 * wv.x;
            rR[i][1] += sr1 * wv.z - si1 * wv.w;
            rI[i][1] += sr1 * wv.w + si1 * wv.z;
        }
    }
    float s0 = (idx[m0] == 0 ? 1.0f : 2.0f) / (float)Lc;
    float s1 = (idx[m0 + 1] == 0 ? 1.0f : 2.0f) / (float)Lc;
    #pragma unroll
    for (int i = 0; i < 4; ++i) {
        _Float16* vp = Vt + ((size_t)bh * 64 + o0 + i) * 128;
        unsigned short r0 = __builtin_bit_cast(unsigned short, (_Float16)(rR[i][0] * s0));
        unsigned short r1 = __builtin_bit_cast(unsigned short, (_Float16)(rR[i][1] * s1));
        unsigned short i0 = __builtin_bit_cast(unsigned short, (_Float16)(-rI[i][0] * s0));
        unsigned short i1 = __builtin_bit_cast(unsigned short, (_Float16)(-rI[i][1] * s1));
        *(unsigned int*)&vp[m0]      = r0 | ((unsigned int)r1 << 16);
        *(unsigned int*)&vp[64 + m0] = i0 | ((unsigned int)i1 << 16);
    }
}

// ---------------------------------------------------------------------------
// Inverse: out[bh][l][o] = sum_{m2} UL[l][m2] * V[m2][o]
// grid (BHc, 16), 256 thr. Wave w owns l rows [64w, 64w+64) of a 256-l block.
// Vt staged in LDS [o][136] (17-bank stride).
// ---------------------------------------------------------------------------
__global__ __launch_bounds__(256) void inv_k(const _Float16* __restrict__ UL,
                                             const _Float16* __restrict__ Vt,
                                             float* __restrict__ out) {
    __shared__ _Float16 vs[64 * 136];          // 17.4KB
    int bh = blockIdx.x, lb = blockIdx.y;
    int tid = threadIdx.x, lane = tid & 63, w = tid >> 6;
    int lo16 = lane & 15, kg = lane >> 4;
    #pragma unroll
    for (int i = 0; i < 4; ++i) {
        int f = i * 256 + tid;                 // 1024 chunks of 8 f16
        int row = f >> 4, seg = f & 15;
        uint4 t4 = *(const uint4*)(Vt + (size_t)bh * 8192 + row * 128 + seg * 8);
        *(uint4*)&vs[row * 136 + seg * 8] = t4;
    }
    __syncthreads();
    int lt0 = lb * 256 + w * 64;
    const _Float16* up = UL + (size_t)(lt0 + lo16) * 128 + kg * 8;
    f32x4 acc[4][4] = {};
    #pragma unroll
    for (int ks = 0; ks < 4; ++ks) {
        half8 Af[4];
        #pragma unroll
        for (int a = 0; a < 4; ++a)
            Af[a] = *(const half8*)(up + (size_t)a * 16 * 128 + ks * 32);
        #pragma unroll
        for (int j = 0; j < 4; ++j) {
            half8 Bf = *(const half8*)&vs[(16 * j + lo16) * 136 + ks * 32 + kg * 8];
            #pragma unroll
            for (int a = 0; a < 4; ++a)
                acc[a][j] = __builtin_amdgcn_mfma_f32_16x16x32_f16(Af[a], Bf, acc[a][j], 0, 0, 0);
        }
    }
    float* op = out + ((size_t)bh * Lc + lt0) * Ec;
    #pragma unroll
    for (int a = 0; a < 4; ++a)
        #pragma unroll
        for (int j = 0; j < 4; ++j)
            #pragma unroll
            for (int r = 0; r < 4; ++r) {
                int ll = a * 16 + kg * 4 + r;
                int o  = 16 * j + lo16;
                op[ll * Ec + o] = acc[a][j][r];
            }
}

// ---------------------------------------------------------------------------
extern "C" void kernel_launch(void* const* d_in, const int* in_sizes, int n_in,
                              void* d_out, int out_size, void* d_ws, size_t ws_size,
                              hipStream_t stream) {
    const float* x   = (const float*)d_in[0];
    const float* wgt = (const float*)d_in[1];
    const int*   idx = (const int*)d_in[2];
    float* out = (float*)d_out;

    // workspace layout: selP (nch*4MB) | Tt (1MB) | UL (1MB) | Vt (2MB)
    size_t need8 = (size_t)8 * BHc * 8192 * 4 + (2ull * 128 * Lc + (size_t)BHc * 8192) * 2;
    int nch = (ws_size >= need8) ? 8 : 4;

    char* ws = (char*)d_ws;
    float*    selP = (float*)ws;
    _Float16* Tt   = (_Float16*)(ws + (size_t)nch * BHc * 8192 * 4);
    _Float16* UL   = Tt + (size_t)128 * Lc;
    _Float16* Vt   = UL + (size_t)Lc * 128;

    twid_k<<<2048, 256, 0, stream>>>(idx, Tt, UL);
    if (nch == 8)
        fwd_k<8><<<dim3(BHc, 8), 256, 0, stream>>>(x, Tt, selP);
    else
        fwd_k<4><<<dim3(BHc, 4), 256, 0, stream>>>(x, Tt, selP);
    mix_k<<<dim3(BHc, 2), 256, 0, stream>>>(selP, wgt, idx, Vt, nch);
    inv_k<<<dim3(BHc, 16), 256, 0, stream>>>(UL, Vt, out);
}

// Round 10
// 123.030 us; speedup vs baseline: 1.0523x; 1.0523x over previous
//
#include <hip/hip_runtime.h>

using half8 = __attribute__((ext_vector_type(8))) _Float16;
using f32x4 = __attribute__((ext_vector_type(4))) float;

#define Lc 4096
#define Ec 64
#define Mc 64
#define BHc 128

// 2*pi/4096
#define TWO_PI_OVER_L 1.5339807878856412e-3f

// ---------------------------------------------------------------------------
// Twiddle tables, both coalesced:
//   Tt[m2][l]  f16, m2 in [0,128): rows 0..63 = cos(th), rows 64..127 = -sin(th)
//   UL[l][m2]  f16: cols 0..63 = cos(th), cols 64..127 = +sin(th)
// th = 2*pi*k_m*l/L
// ---------------------------------------------------------------------------
__global__ __launch_bounds__(256) void twid_k(const int* __restrict__ idx,
                                              _Float16* __restrict__ Tt,
                                              _Float16* __restrict__ UL) {
    int id = blockIdx.x * 256 + threadIdx.x;   // 0 .. 524287
    {   // UL pass: l = id>>7, m2 = id&127  (coalesced in m2)
        int l = id >> 7, m2 = id & 127, m = m2 & 63;
        int k = idx[m];
        int ph = (k * l) & (Lc - 1);
        float s, c;
        sincosf((float)ph * TWO_PI_OVER_L, &s, &c);
        UL[id] = (_Float16)((m2 >= 64) ? s : c);
    }
    {   // Tt pass: m2 = id>>12, l = id&4095  (coalesced in l)
        int m2 = id >> 12, l = id & 4095, m = m2 & 63;
        int k = idx[m];
        int ph = (k * l) & (Lc - 1);
        float s, c;
        sincosf((float)ph * TWO_PI_OVER_L, &s, &c);
        Tt[id] = (_Float16)((m2 >= 64) ? -s : c);
    }
}

// ---------------------------------------------------------------------------
// Forward: selP[ch][bh][m2=128][e=64] = sum_{l in chunk} Tt[m2][l] * x[bh][l][e]
// grid (BHc, NCH), 256 thr (4 waves). Wave w owns m2 rows [32w, 32w+32).
// r8 pipeline: double-buffered LDS (1 barrier/tile) + 2-tile-ahead register
// prefetch with two register sets. (Best-known fwd, 128.2 us total.)
// xs layout: [e][l] f16, row = 128B, byte ^= ((e&7)<<4).
// ---------------------------------------------------------------------------
#define LOADT(SET, S) do{                                                     \
    const float* g0_ = xp + (size_t)((S) * 64 + 2 * lp) * Ec;                 \
    const float* g1_ = xp + (size_t)((S) * 64 + 2 * lp + 32) * Ec;            \
    ra[SET][0] = *(const float4*)g0_;  rb[SET][0] = *(const float4*)(g0_ + Ec);\
    ra[SET][1] = *(const float4*)g1_;  rb[SET][1] = *(const float4*)(g1_ + Ec);\
}while(0)

#define PACKT(SET, BUF) do{                                                   \
    _Pragma("unroll")                                                         \
    for (int i_ = 0; i_ < 2; ++i_) {                                          \
        const float* pa_ = (const float*)&ra[SET][i_];                        \
        const float* pb_ = (const float*)&rb[SET][i_];                        \
        unsigned int pk_[4];                                                  \
        _Pragma("unroll")                                                     \
        for (int j_ = 0; j_ < 4; ++j_) {                                      \
            unsigned short ua_ = __builtin_bit_cast(unsigned short, (_Float16)pa_[j_]); \
            unsigned short ub_ = __builtin_bit_cast(unsigned short, (_Float16)pb_[j_]); \
            pk_[j_] = ua_ | ((unsigned int)ub_ << 16);                        \
        }                                                                     \
        _Pragma("unroll")                                                     \
        for (int j_ = 0; j_ < 4; ++j_) {                                      \
            int jr_ = (j_ + col4) & 3;                                        \
            int e_  = col4 * 4 + jr_;                                         \
            int byt_ = (e_ * 128 + lp * 4 + i_ * 64) ^ ((e_ & 7) << 4);       \
            *(unsigned int*)((char*)xs[BUF] + byt_) = pk_[jr_];               \
        }                                                                     \
    }                                                                         \
}while(0)

#define MFMA_STEP(S, BUF) do{                                                 \
    _Pragma("unroll")                                                         \
    for (int ks_ = 0; ks_ < 2; ++ks_) {                                       \
        half8 A0_ = *(const half8*)(tp + (S) * 64 + ks_ * 32);                \
        half8 A1_ = *(const half8*)(tp + (size_t)16 * Lc + (S) * 64 + ks_ * 32); \
        _Pragma("unroll")                                                     \
        for (int j_ = 0; j_ < 4; ++j_) {                                      \
            int rbyt_ = ((16 * j_ + lo16) * 128 + ks_ * 64 + kg * 16) ^ ((lo16 & 7) << 4); \
            half8 Bv_ = *(const half8*)((const char*)xs[BUF] + rbyt_);        \
            acc[0][j_] = __builtin_amdgcn_mfma_f32_16x16x32_f16(A0_, Bv_, acc[0][j_], 0, 0, 0); \
            acc[1][j_] = __builtin_amdgcn_mfma_f32_16x16x32_f16(A1_, Bv_, acc[1][j_], 0, 0, 0); \
        }                                                                     \
    }                                                                         \
}while(0)

template<int NCH>
__global__ __launch_bounds__(256) void fwd_k(const float* __restrict__ x,
                                             const _Float16* __restrict__ Tt,
                                             float* __restrict__ selP) {
    constexpr int CH = Lc / NCH;
    constexpr int NT = CH / 64;                // 8 at NCH=8 (even)
    __shared__ _Float16 xs[2][64 * 64];        // 2 x 8KB
    int bh = blockIdx.x, ch = blockIdx.y;
    int tid = threadIdx.x;
    int lane = tid & 63, w = tid >> 6;
    int lo16 = lane & 15, kg = lane >> 4;
    int col4 = tid & 15, lp = tid >> 4;        // staging: e4=col4*4, row-pair lp

    const float* xp = x + ((size_t)bh * Lc + (size_t)ch * CH) * Ec + col4 * 4;
    const _Float16* tp = Tt + (size_t)(w * 32 + lo16) * Lc + ch * CH + kg * 8;

    float4 ra[2][2], rb[2][2];                 // [regset][i]
    LOADT(0, 0);                               // tile 0 -> set0
    LOADT(1, 1);                               // tile 1 -> set1
    PACKT(0, 0);                               // tile 0 -> buf0
    __syncthreads();

    f32x4 acc[2][4] = {};
    for (int t = 0; t < NT / 2; ++t) {
        int s0 = 2 * t, s1 = 2 * t + 1;
        // ---- even tile: compute buf0 (tile s0), fill buf1 (tile s0+1) ----
        if (s0 + 2 < NT) LOADT(0, s0 + 2);     // tile s0+2 -> set0 (free)
        PACKT(1, 1);                           // tile s0+1 (set1) -> buf1
        MFMA_STEP(s0, 0);
        __syncthreads();
        // ---- odd tile: compute buf1 (tile s1), fill buf0 (tile s1+1) ----
        if (s1 + 2 < NT) LOADT(1, s1 + 2);     // tile s1+2 -> set1 (free)
        if (s1 + 1 < NT) PACKT(0, 0);          // tile s1+1 (set0) -> buf0
        MFMA_STEP(s1, 1);
        __syncthreads();
    }

    float* op = selP + (size_t)(ch * BHc + bh) * (128 * Ec);
    #pragma unroll
    for (int a = 0; a < 2; ++a)
        #pragma unroll
        for (int j = 0; j < 4; ++j)
            #pragma unroll
            for (int r = 0; r < 4; ++r) {
                int m2 = w * 32 + a * 16 + kg * 4 + r;
                int e  = 16 * j + lo16;
                op[m2 * Ec + e] = acc[a][j][r];
            }
}

// ---------------------------------------------------------------------------
// Mix v2: reduce K-partials, apply complex weight einsum, fold irfft scale.
// Vt[bh][o=64][m2=128] f16: cols 0..63 = s*Re(out_sel), 64..127 = -s*Im(out_sel)
// r10 change: grid (BHc, 2 oh, 2 mh) = 512 blocks (2/CU, was 1/CU), stage only
// the needed 64 selP rows (16.6KB LDS), e-loop unrolled x8 for ILP.
// Thread owns 2 o x 2 m (og=tid&15, mg=tid>>4).
// ---------------------------------------------------------------------------
__global__ __launch_bounds__(256) void mix_k(const float* __restrict__ selP,
                                             const float* __restrict__ wgt,
                                             const int* __restrict__ idx,
                                             _Float16* __restrict__ Vt, int nch) {
    __shared__ float sel_s[64 * 65];           // rows 0..31 Re, 32..63 Im; 16.6KB
    int bh = blockIdx.x, oh = blockIdx.y, mh = blockIdx.z;
    int tid = threadIdx.x;
    #pragma unroll
    for (int i = 0; i < 4; ++i) {
        int f4 = i * 256 + tid;                // 1024 float4 = 64 rows x 64 e
        int lr = f4 >> 4, e4 = (f4 & 15) * 4;
        int m2 = (lr < 32) ? (mh * 32 + lr) : (64 + mh * 32 + (lr - 32));
        float4 a = make_float4(0.f, 0.f, 0.f, 0.f);
        for (int chn = 0; chn < nch; ++chn) {
            float4 v = *(const float4*)(selP + (size_t)(chn * BHc + bh) * 8192
                                             + (size_t)m2 * Ec + e4);
            a.x += v.x; a.y += v.y; a.z += v.z; a.w += v.w;
        }
        float* dst = &sel_s[lr * 65 + e4];
        dst[0] = a.x; dst[1] = a.y; dst[2] = a.z; dst[3] = a.w;
    }
    __syncthreads();
    int og = tid & 15, mg = tid >> 4;
    int o0 = oh * 32 + og * 2;                 // 2 o per thread
    int m0 = mh * 32 + mg * 2;                 // 2 m per thread (global m)
    int lm = mg * 2;                           // local Re row
    float rR[2][2] = {{0}}, rI[2][2] = {{0}};
    #pragma unroll 8
    for (int e = 0; e < Ec; ++e) {
        float sr0 = sel_s[lm * 65 + e];
        float sr1 = sel_s[(lm + 1) * 65 + e];
        float si0 = sel_s[(32 + lm) * 65 + e];
        float si1 = sel_s[(32 + lm + 1) * 65 + e];
        #pragma unroll
        for (int i = 0; i < 2; ++i) {
            const float4* wp = (const float4*)&wgt[(((size_t)e * Ec + (o0 + i)) * Mc + m0) * 2];
            float4 wv = *wp;   // wR[m0], wI[m0], wR[m0+1], wI[m0+1]
            rR[i][0] += sr0 * wv.x - si0 * wv.y;
            rI[i][0] += sr0 * wv.y + si0 * wv.x;
            rR[i][1] += sr1 * wv.z - si1 * wv.w;
            rI[i][1] += sr1 * wv.w + si1 * wv.z;
        }
    }
    float s0 = (idx[m0] == 0 ? 1.0f : 2.0f) / (float)Lc;
    float s1 = (idx[m0 + 1] == 0 ? 1.0f : 2.0f) / (float)Lc;
    #pragma unroll
    for (int i = 0; i < 2; ++i) {
        _Float16* vp = Vt + ((size_t)bh * 64 + o0 + i) * 128;
        unsigned short r0 = __builtin_bit_cast(unsigned short, (_Float16)(rR[i][0] * s0));
        unsigned short r1 = __builtin_bit_cast(unsigned short, (_Float16)(rR[i][1] * s1));
        unsigned short i0 = __builtin_bit_cast(unsigned short, (_Float16)(-rI[i][0] * s0));
        unsigned short i1 = __builtin_bit_cast(unsigned short, (_Float16)(-rI[i][1] * s1));
        *(unsigned int*)&vp[m0]      = r0 | ((unsigned int)r1 << 16);
        *(unsigned int*)&vp[64 + m0] = i0 | ((unsigned int)i1 << 16);
    }
}

// ---------------------------------------------------------------------------
// Inverse: out[bh][l][o] = sum_{m2} UL[l][m2] * V[m2][o]
// grid (BHc, 16), 256 thr. Wave w owns l rows [64w, 64w+64) of a 256-l block.
// Vt staged in LDS [o][136] (17-bank stride).
// ---------------------------------------------------------------------------
__global__ __launch_bounds__(256) void inv_k(const _Float16* __restrict__ UL,
                                             const _Float16* __restrict__ Vt,
                                             float* __restrict__ out) {
    __shared__ _Float16 vs[64 * 136];          // 17.4KB
    int bh = blockIdx.x, lb = blockIdx.y;
    int tid = threadIdx.x, lane = tid & 63, w = tid >> 6;
    int lo16 = lane & 15, kg = lane >> 4;
    #pragma unroll
    for (int i = 0; i < 4; ++i) {
        int f = i * 256 + tid;                 // 1024 chunks of 8 f16
        int row = f >> 4, seg = f & 15;
        uint4 t4 = *(const uint4*)(Vt + (size_t)bh * 8192 + row * 128 + seg * 8);
        *(uint4*)&vs[row * 136 + seg * 8] = t4;
    }
    __syncthreads();
    int lt0 = lb * 256 + w * 64;
    const _Float16* up = UL + (size_t)(lt0 + lo16) * 128 + kg * 8;
    f32x4 acc[4][4] = {};
    #pragma unroll
    for (int ks = 0; ks < 4; ++ks) {
        half8 Af[4];
        #pragma unroll
        for (int a = 0; a < 4; ++a)
            Af[a] = *(const half8*)(up + (size_t)a * 16 * 128 + ks * 32);
        #pragma unroll
        for (int j = 0; j < 4; ++j) {
            half8 Bf = *(const half8*)&vs[(16 * j + lo16) * 136 + ks * 32 + kg * 8];
            #pragma unroll
            for (int a = 0; a < 4; ++a)
                acc[a][j] = __builtin_amdgcn_mfma_f32_16x16x32_f16(Af[a], Bf, acc[a][j], 0, 0, 0);
        }
    }
    float* op = out + ((size_t)bh * Lc + lt0) * Ec;
    #pragma unroll
    for (int a = 0; a < 4; ++a)
        #pragma unroll
        for (int j = 0; j < 4; ++j)
            #pragma unroll
            for (int r = 0; r < 4; ++r) {
                int ll = a * 16 + kg * 4 + r;
                int o  = 16 * j + lo16;
                op[ll * Ec + o] = acc[a][j][r];
            }
}

// ---------------------------------------------------------------------------
extern "C" void kernel_launch(void* const* d_in, const int* in_sizes, int n_in,
                              void* d_out, int out_size, void* d_ws, size_t ws_size,
                              hipStream_t stream) {
    const float* x   = (const float*)d_in[0];
    const float* wgt = (const float*)d_in[1];
    const int*   idx = (const int*)d_in[2];
    float* out = (float*)d_out;

    // workspace layout: selP (nch*4MB) | Tt (1MB) | UL (1MB) | Vt (2MB)
    size_t need8 = (size_t)8 * BHc * 8192 * 4 + (2ull * 128 * Lc + (size_t)BHc * 8192) * 2;
    int nch = (ws_size >= need8) ? 8 : 4;

    char* ws = (char*)d_ws;
    float*    selP = (float*)ws;
    _Float16* Tt   = (_Float16*)(ws + (size_t)nch * BHc * 8192 * 4);
    _Float16* UL   = Tt + (size_t)128 * Lc;
    _Float16* Vt   = UL + (size_t)Lc * 128;

    twid_k<<<2048, 256, 0, stream>>>(idx, Tt, UL);
    if (nch == 8)
        fwd_k<8><<<dim3(BHc, 8), 256, 0, stream>>>(x, Tt, selP);
    else
        fwd_k<4><<<dim3(BHc, 4), 256, 0, stream>>>(x, Tt, selP);
    mix_k<<<dim3(BHc, 2, 2), 256, 0, stream>>>(selP, wgt, idx, Vt, nch);
    inv_k<<<dim3(BHc, 16), 256, 0, stream>>>(UL, Vt, out);
}